// Round 7
// baseline (698.620 us; speedup 1.0000x reference)
//
#include <hip/hip_runtime.h>

// Geodesic shooting (Hamiltonian RK4) on MI355X.
// dyn(s) = [K@m, 2 * sum_j (mi.mj) Kij (ci - cj)], K = exp(-||ci-cj||^2), sigma=1.
// j-stream is wave-uniform -> scalar (SGPR) loads from a packed mirror; no LDS in dyn.
// PTS=4 i-points per thread for ILP between scalar-load waits.

#define CN   8192
#define TPB  256
#define PTS  4
#define IGRP (TPB * PTS)    // 1024 i's per block
#define NIB  (CN / IGRP)    // 8 i-groups
#define SSZ  (2 * CN * 3)   // floats per state

// sqrt(log2(e)): coords pre-scaled so exp(-||.||^2) == exp2(-d2_scaled).
#define CSCALE 1.2011224087864498f
#define FSCALE (2.0f / CSCALE)

// packed mirror: [CN][2] float4 = {c'x,c'y,c'z,0},{mx,my,mz,0}

__global__ __launch_bounds__(TPB, 4) void dyn_partial_kernel(
    const float4* __restrict__ jp, float* __restrict__ part, int jchunk)
{
    const int tid = threadIdx.x;
    const int i0  = blockIdx.x * IGRP + tid;

    float cx[PTS], cy[PTS], cz[PTS], mx[PTS], my[PTS], mz[PTS];
    float gx[PTS], gy[PTS], gz[PTS], fx[PTS], fy[PTS], fz[PTS];
#pragma unroll
    for (int q = 0; q < PTS; ++q) {
        const float4 C = jp[2 * (i0 + q * TPB)];
        const float4 P = jp[2 * (i0 + q * TPB) + 1];
        cx[q] = C.x; cy[q] = C.y; cz[q] = C.z;
        mx[q] = P.x; my[q] = P.y; mz[q] = P.z;
        gx[q] = 0.f; gy[q] = 0.f; gz[q] = 0.f;
        fx[q] = 0.f; fy[q] = 0.f; fz[q] = 0.f;
    }

    const int jbeg = blockIdx.y * jchunk;
    const int jend = jbeg + jchunk;
#pragma unroll 2
    for (int j = jbeg; j < jend; ++j) {
        const float4 A = jp[2*j];       // uniform -> s_load (SGPRs)
        const float4 M = jp[2*j+1];
#pragma unroll
        for (int q = 0; q < PTS; ++q) {
            const float dx = cx[q] - A.x, dy = cy[q] - A.y, dz = cz[q] - A.z;
            const float d2 = fmaf(dx, dx, fmaf(dy, dy, dz*dz));
            const float e  = __builtin_amdgcn_exp2f(-d2);
            const float md = fmaf(mx[q], M.x, fmaf(my[q], M.y, mz[q] * M.z));
            const float w  = md * e;
            gx[q] = fmaf(e, M.x, gx[q]); gy[q] = fmaf(e, M.y, gy[q]); gz[q] = fmaf(e, M.z, gz[q]);
            fx[q] = fmaf(w, dx, fx[q]);  fy[q] = fmaf(w, dy, fy[q]);  fz[q] = fmaf(w, dz, fz[q]);
        }
    }
    // dm = 2*force_true = FSCALE * f   (dx was in scaled units)
    float* p = part + (size_t)blockIdx.y * (6 * CN);
#pragma unroll
    for (int q = 0; q < PTS; ++q) {
        const int i = i0 + q * TPB;
        p[0*CN+i] = gx[q];        p[1*CN+i] = gy[q];        p[2*CN+i] = gz[q];
        p[3*CN+i] = FSCALE*fx[q]; p[4*CN+i] = FSCALE*fy[q]; p[5*CN+i] = FSCALE*fz[q];
    }
}

// gidx in [0, 6*CN): plane cd = gidx>>13, i = gidx&8191
__device__ __forceinline__ void decode(int gidx, int& off, int& i, int& comp, int& d) {
    const int cd = gidx >> 13;
    i    = gidx & (CN - 1);
    comp = (cd >= 3) ? 1 : 0;
    d    = cd - comp * 3;
    off  = comp * CN * 3 + i * 3 + d;
}

// Reduce partials over S; store k and packed(sbase + coef*k).
template<int S>
__global__ __launch_bounds__(256) void finish_kernel(
    const float* __restrict__ part, float* __restrict__ kout,
    const float* __restrict__ sbase, float* __restrict__ packed, float coef)
{
    constexpr int SQ = S / 4;
    const int tid = threadIdx.x;
    const int sub = tid >> 6, o = tid & 63;
    const int idx = blockIdx.x * 64 + o;
    const float* p = part + (size_t)(sub * SQ) * (6 * CN) + idx;
    float acc = 0.f;
#pragma unroll 8
    for (int r = 0; r < SQ; ++r) acc += p[(size_t)r * (6 * CN)];
    __shared__ float red[256];
    red[tid] = acc;
    __syncthreads();
    if (tid < 64) {
        const float total = red[tid] + red[tid+64] + red[tid+128] + red[tid+192];
        int off, i, comp, d;
        decode(blockIdx.x * 64 + tid, off, i, comp, d);
        kout[off] = total;
        const float v = sbase[off] + coef * total;
        packed[i*8 + comp*4 + d] = comp ? v : v * CSCALE;
    }
}

// 4th finish fused with RK4 combine: scur += dt/6*(k1+2k2+2k3+k4); packed(scur); echo out.
template<int S>
__global__ __launch_bounds__(256) void finish_final_kernel(
    const float* __restrict__ part,
    const float* __restrict__ k1, const float* __restrict__ k2, const float* __restrict__ k3,
    float* __restrict__ scur, float* __restrict__ packed,
    float* __restrict__ outslot, float dt6)
{
    constexpr int SQ = S / 4;
    const int tid = threadIdx.x;
    const int sub = tid >> 6, o = tid & 63;
    const int idx = blockIdx.x * 64 + o;
    const float* p = part + (size_t)(sub * SQ) * (6 * CN) + idx;
    float acc = 0.f;
#pragma unroll 8
    for (int r = 0; r < SQ; ++r) acc += p[(size_t)r * (6 * CN)];
    __shared__ float red[256];
    red[tid] = acc;
    __syncthreads();
    if (tid < 64) {
        const float k4 = red[tid] + red[tid+64] + red[tid+128] + red[tid+192];
        int off, i, comp, d;
        decode(blockIdx.x * 64 + tid, off, i, comp, d);
        const float v = scur[off] + dt6 * (k1[off] + 2.f * (k2[off] + k3[off]) + k4);
        scur[off]    = v;
        outslot[off] = v;
        packed[i*8 + comp*4 + d] = comp ? v : v * CSCALE;
    }
}

__global__ __launch_bounds__(256) void init_kernel(
    const float* __restrict__ mom, const float* __restrict__ cp,
    float* __restrict__ out, float* __restrict__ scur, float* __restrict__ packed)
{
    const int idx = blockIdx.x * 256 + threadIdx.x;
    if (idx < 5) out[idx] = 0.25f * (float)idx;      // t_span
    if (idx < CN * 3) {
        const float cv = cp[idx], mv = mom[idx];
        scur[idx]          = cv;
        scur[CN * 3 + idx] = mv;
        out[5 + idx]            = cv;
        out[5 + CN * 3 + idx]   = mv;
        const int i = idx / 3, d = idx - i * 3;
        packed[i*8 + d]     = cv * CSCALE;
        packed[i*8 + 4 + d] = mv;
        if (d == 0) { packed[i*8 + 3] = 0.f; packed[i*8 + 7] = 0.f; }
    }
}

template<int S>
static void run_steps(const float* mom, const float* cp, float* out,
                      float* scur, float* kb0, float* kb1, float* kb2,
                      float* packed, float* part, hipStream_t stream)
{
    const float dt = 0.25f;
    const int jchunk = CN / S;
    const float4* jp = (const float4*)packed;
    init_kernel<<<(CN * 3 + 255) / 256, 256, 0, stream>>>(mom, cp, out, scur, packed);
    dim3 dgrid(NIB, S);
    const int fgrid = 6 * CN / 64;   // 768
    for (int step = 0; step < 4; ++step) {
        float* outslot = out + 5 + (size_t)(step + 1) * SSZ;
        dyn_partial_kernel<<<dgrid, TPB, 0, stream>>>(jp, part, jchunk);
        finish_kernel<S><<<fgrid, 256, 0, stream>>>(part, kb0, scur, packed, 0.5f * dt);
        dyn_partial_kernel<<<dgrid, TPB, 0, stream>>>(jp, part, jchunk);
        finish_kernel<S><<<fgrid, 256, 0, stream>>>(part, kb1, scur, packed, 0.5f * dt);
        dyn_partial_kernel<<<dgrid, TPB, 0, stream>>>(jp, part, jchunk);
        finish_kernel<S><<<fgrid, 256, 0, stream>>>(part, kb2, scur, packed, dt);
        dyn_partial_kernel<<<dgrid, TPB, 0, stream>>>(jp, part, jchunk);
        finish_final_kernel<S><<<fgrid, 256, 0, stream>>>(part, kb0, kb1, kb2, scur, packed,
                                                          outslot, dt / 6.f);
    }
}

extern "C" void kernel_launch(void* const* d_in, const int* in_sizes, int n_in,
                              void* d_out, int out_size, void* d_ws, size_t ws_size,
                              hipStream_t stream)
{
    const float* mom = (const float*)d_in[0];
    const float* cp  = (const float*)d_in[1];
    float* out = (float*)d_out;
    float* ws  = (float*)d_ws;

    float* scur   = ws;
    float* kb0    = ws + SSZ;
    float* kb1    = ws + 2 * SSZ;
    float* kb2    = ws + 3 * SSZ;
    float* packed = ws + 4 * SSZ;          // CN*8
    float* part   = packed + CN * 8;       // S * 6 * CN

    const size_t fixed = 4 * SSZ + CN * 8;
    const size_t avail_f = ws_size / sizeof(float);
    int S = 128;
    while (S > 4 && fixed + (size_t)S * 6 * CN > avail_f) S >>= 1;

    switch (S) {
        case 128: run_steps<128>(mom, cp, out, scur, kb0, kb1, kb2, packed, part, stream); break;
        case 64:  run_steps<64 >(mom, cp, out, scur, kb0, kb1, kb2, packed, part, stream); break;
        case 32:  run_steps<32 >(mom, cp, out, scur, kb0, kb1, kb2, packed, part, stream); break;
        case 16:  run_steps<16 >(mom, cp, out, scur, kb0, kb1, kb2, packed, part, stream); break;
        default:  run_steps<8  >(mom, cp, out, scur, kb0, kb1, kb2, packed, part, stream); break;
    }
}

// Round 9
// 605.759 us; speedup vs baseline: 1.1533x; 1.1533x over previous
//
#include <hip/hip_runtime.h>

// Geodesic shooting (Hamiltonian RK4) on MI355X.
// dyn(s) = [K@m, 2 * sum_j (mi.mj) Kij (ci - cj)], K = exp(-||ci-cj||^2), sigma=1.
// This version: dyn accumulates k directly via global fp32 atomics (plane-major k[6][CN]),
// computes its own stmp = scur + coef*k_prev on the fly (j-chunk staged to LDS, broadcast
// ds_read_b128 -> in-order lgkmcnt, pipelinable), so the graph is 21 dispatches:
// init + 16*dyn + 4*advance.

#define CN   8192
#define TPB  256
#define PTS  2
#define IGRP (TPB * PTS)    // 512 i's per block
#define NIB  (CN / IGRP)    // 16 i-groups
#define SJ   128            // j-splits
#define JC   (CN / SJ)      // 64 j's per block
#define SSZ  (2 * CN * 3)   // floats per state

// sqrt(log2(e)): coords pre-scaled so exp(-||.||^2) == exp2(-d2_scaled).
#define CSCALE 1.2011224087864498f
#define FSCALE (2.0f / CSCALE)

// k layout (atomic-friendly): k[plane*CN + i], planes 0..2 = dc, 3..5 = dm.

__global__ __launch_bounds__(TPB, 8) void dyn_kernel(
    const float* __restrict__ scur, const float* __restrict__ kprev,
    float coef, float* __restrict__ kout)
{
    __shared__ float4 jt[JC][2];   // [0]={c'x,c'y,c'z,0} scaled, [1]={mx,my,mz,0}
    const int tid = threadIdx.x;
    const int jbase = blockIdx.y * JC;

    // Stage this block's j-chunk: stmp = scur + coef*kprev, c-part scaled by CSCALE.
    {
        float* jf = (float*)jt;
#pragma unroll
        for (int q = tid; q < JC * 8; q += TPB) {
            const int p = jbase + (q >> 3), s = q & 7;
            float v = 0.f;
            if (s < 3) {
                v = (scur[p*3 + s] + coef * kprev[s*CN + p]) * CSCALE;
            } else if (s >= 4 && s < 7) {
                const int d = s - 4;
                v = scur[CN*3 + p*3 + d] + coef * kprev[(3 + d)*CN + p];
            }
            jf[q] = v;
        }
    }

    // i-point data (same on-the-fly stmp), PTS=2 points per thread.
    const int i0 = blockIdx.x * IGRP + tid;
    const int i1 = i0 + TPB;
    const float cx0 = (scur[i0*3+0] + coef*kprev[0*CN+i0]) * CSCALE;
    const float cy0 = (scur[i0*3+1] + coef*kprev[1*CN+i0]) * CSCALE;
    const float cz0 = (scur[i0*3+2] + coef*kprev[2*CN+i0]) * CSCALE;
    const float mx0 =  scur[CN*3+i0*3+0] + coef*kprev[3*CN+i0];
    const float my0 =  scur[CN*3+i0*3+1] + coef*kprev[4*CN+i0];
    const float mz0 =  scur[CN*3+i0*3+2] + coef*kprev[5*CN+i0];
    const float cx1 = (scur[i1*3+0] + coef*kprev[0*CN+i1]) * CSCALE;
    const float cy1 = (scur[i1*3+1] + coef*kprev[1*CN+i1]) * CSCALE;
    const float cz1 = (scur[i1*3+2] + coef*kprev[2*CN+i1]) * CSCALE;
    const float mx1 =  scur[CN*3+i1*3+0] + coef*kprev[3*CN+i1];
    const float my1 =  scur[CN*3+i1*3+1] + coef*kprev[4*CN+i1];
    const float mz1 =  scur[CN*3+i1*3+2] + coef*kprev[5*CN+i1];

    float gx0=0.f,gy0=0.f,gz0=0.f, fx0=0.f,fy0=0.f,fz0=0.f;
    float gx1=0.f,gy1=0.f,gz1=0.f, fx1=0.f,fy1=0.f,fz1=0.f;

    __syncthreads();

#pragma unroll 4
    for (int j = 0; j < JC; ++j) {
        const float4 A = jt[j][0];   // broadcast ds_read_b128
        const float4 M = jt[j][1];
        {
            const float dx = cx0 - A.x, dy = cy0 - A.y, dz = cz0 - A.z;
            const float d2 = fmaf(dx, dx, fmaf(dy, dy, dz*dz));
            const float e  = __builtin_amdgcn_exp2f(-d2);
            const float md = fmaf(mx0, M.x, fmaf(my0, M.y, mz0 * M.z));
            const float w  = md * e;
            gx0 = fmaf(e, M.x, gx0); gy0 = fmaf(e, M.y, gy0); gz0 = fmaf(e, M.z, gz0);
            fx0 = fmaf(w, dx, fx0);  fy0 = fmaf(w, dy, fy0);  fz0 = fmaf(w, dz, fz0);
        }
        {
            const float dx = cx1 - A.x, dy = cy1 - A.y, dz = cz1 - A.z;
            const float d2 = fmaf(dx, dx, fmaf(dy, dy, dz*dz));
            const float e  = __builtin_amdgcn_exp2f(-d2);
            const float md = fmaf(mx1, M.x, fmaf(my1, M.y, mz1 * M.z));
            const float w  = md * e;
            gx1 = fmaf(e, M.x, gx1); gy1 = fmaf(e, M.y, gy1); gz1 = fmaf(e, M.z, gz1);
            fx1 = fmaf(w, dx, fx1);  fy1 = fmaf(w, dy, fy1);  fz1 = fmaf(w, dz, fz1);
        }
    }

    // dm = 2*force_true = FSCALE * f (dx in scaled units). 128 adds/address, fp32 noise ~1e-6.
    atomicAdd(&kout[0*CN+i0], gx0); atomicAdd(&kout[1*CN+i0], gy0); atomicAdd(&kout[2*CN+i0], gz0);
    atomicAdd(&kout[3*CN+i0], FSCALE*fx0); atomicAdd(&kout[4*CN+i0], FSCALE*fy0); atomicAdd(&kout[5*CN+i0], FSCALE*fz0);
    atomicAdd(&kout[0*CN+i1], gx1); atomicAdd(&kout[1*CN+i1], gy1); atomicAdd(&kout[2*CN+i1], gz1);
    atomicAdd(&kout[3*CN+i1], FSCALE*fx1); atomicAdd(&kout[4*CN+i1], FSCALE*fy1); atomicAdd(&kout[5*CN+i1], FSCALE*fz1);
}

// RK4 combine + output echo + k-rezero. idx over [0, 6*CN): plane = idx>>13, i = idx&8191.
__global__ __launch_bounds__(256) void advance_kernel(
    float* __restrict__ scur,
    float* __restrict__ k1, float* __restrict__ k2,
    float* __restrict__ k3, float* __restrict__ k4,
    float* __restrict__ outslot, float dt6)
{
    const int idx = blockIdx.x * 256 + threadIdx.x;
    if (idx >= 6 * CN) return;
    const int plane = idx >> 13, i = idx & (CN - 1);
    const int comp = (plane >= 3) ? 1 : 0, d = plane - comp * 3;
    const int off = comp * CN * 3 + i * 3 + d;
    const float v = scur[off] + dt6 * (k1[idx] + 2.f * (k2[idx] + k3[idx]) + k4[idx]);
    scur[off]    = v;
    outslot[off] = v;
    k1[idx] = 0.f; k2[idx] = 0.f; k3[idx] = 0.f; k4[idx] = 0.f;
}

__global__ __launch_bounds__(256) void init_kernel(
    const float* __restrict__ mom, const float* __restrict__ cp,
    float* __restrict__ out, float* __restrict__ scur,
    float* __restrict__ kb0, float* __restrict__ kb1,
    float* __restrict__ kb2, float* __restrict__ kb3)
{
    const int idx = blockIdx.x * 256 + threadIdx.x;
    if (idx < 5) out[idx] = 0.25f * (float)idx;      // t_span
    if (idx < 6 * CN) { kb0[idx]=0.f; kb1[idx]=0.f; kb2[idx]=0.f; kb3[idx]=0.f; }
    if (idx < CN * 3) {
        const float cv = cp[idx], mv = mom[idx];
        scur[idx]          = cv;
        scur[CN * 3 + idx] = mv;
        out[5 + idx]            = cv;                // st[0][0] = c0
        out[5 + CN * 3 + idx]   = mv;                // st[0][1] = m0
    }
}

extern "C" void kernel_launch(void* const* d_in, const int* in_sizes, int n_in,
                              void* d_out, int out_size, void* d_ws, size_t ws_size,
                              hipStream_t stream)
{
    const float* mom = (const float*)d_in[0];
    const float* cp  = (const float*)d_in[1];
    float* out = (float*)d_out;
    float* ws  = (float*)d_ws;

    float* scur = ws;                       // SSZ
    float* kb0  = ws + SSZ;                 // 6*CN each
    float* kb1  = kb0 + 6 * CN;
    float* kb2  = kb1 + 6 * CN;
    float* kb3  = kb2 + 6 * CN;

    const float dt  = 0.25f;
    const float dt6 = dt / 6.f;

    init_kernel<<<(6 * CN + 255) / 256, 256, 0, stream>>>(mom, cp, out, scur,
                                                          kb0, kb1, kb2, kb3);
    dim3 dgrid(NIB, SJ);
    const int agrid = (6 * CN + 255) / 256;
    for (int step = 0; step < 4; ++step) {
        float* outslot = out + 5 + (size_t)(step + 1) * SSZ;
        dyn_kernel<<<dgrid, TPB, 0, stream>>>(scur, kb0, 0.0f,      kb0);
        dyn_kernel<<<dgrid, TPB, 0, stream>>>(scur, kb0, 0.5f * dt, kb1);
        dyn_kernel<<<dgrid, TPB, 0, stream>>>(scur, kb1, 0.5f * dt, kb2);
        dyn_kernel<<<dgrid, TPB, 0, stream>>>(scur, kb2, dt,        kb3);
        advance_kernel<<<agrid, 256, 0, stream>>>(scur, kb0, kb1, kb2, kb3, outslot, dt6);
    }
}

// Round 10
// 589.470 us; speedup vs baseline: 1.1852x; 1.0276x over previous
//
#include <hip/hip_runtime.h>

// Geodesic shooting (Hamiltonian RK4) on MI355X.
// dyn(s) = [K@m, 2 * sum_j (mi.mj) Kij (ci - cj)], K = exp(-||ci-cj||^2), sigma=1.
// Structure: init + 16*dyn + 4*advance (21 dispatches); k via global fp32 atomics
// into plane-major k[6][CN]. dyn computes stmp = scur + coef*kprev on the fly:
// j-chunk staged to LDS once per block; PTS=4 i-points/thread so the per-CU LDS
// issue cost (waves * jchunk * 24cy) drops below the VALU cost -> VALU-bound.
// Pair math in dot form: d2 = ci2 + cj2 - 2ci.cj; force = ci*W - h (epilogue).

#define CN   8192
#define TPB  256
#define PTS  4
#define IGRP (TPB * PTS)    // 1024 i's per block
#define NIB  (CN / IGRP)    // 8 i-groups
#define SJ   128            // j-splits
#define JC   (CN / SJ)      // 64 j's per block
#define SSZ  (2 * CN * 3)   // floats per state

// sqrt(log2(e)): coords pre-scaled so exp(-||.||^2) == exp2(-d2_scaled).
#define CSCALE 1.2011224087864498f
#define FSCALE (2.0f / CSCALE)

__global__ __launch_bounds__(TPB, 4) void dyn_kernel(
    const float* __restrict__ scur, const float* __restrict__ kprev,
    float coef, float* __restrict__ kout)
{
    __shared__ float4 jt[JC][2];   // [0]={c'x,c'y,c'z,|c'|^2}, [1]={mx,my,mz,0}
    const int tid = threadIdx.x;
    const int jbase = blockIdx.y * JC;

    // Stage this block's j-chunk: stmp = scur + coef*kprev (c-part scaled by CSCALE).
    if (tid < JC) {
        const int p = jbase + tid;
        const float sx = (scur[p*3+0] + coef * kprev[0*CN+p]) * CSCALE;
        const float sy = (scur[p*3+1] + coef * kprev[1*CN+p]) * CSCALE;
        const float sz = (scur[p*3+2] + coef * kprev[2*CN+p]) * CSCALE;
        jt[tid][0] = make_float4(sx, sy, sz, fmaf(sx,sx, fmaf(sy,sy, sz*sz)));
    } else if (tid < 2 * JC) {
        const int p = jbase + tid - JC;
        const float mx = scur[CN*3+p*3+0] + coef * kprev[3*CN+p];
        const float my = scur[CN*3+p*3+1] + coef * kprev[4*CN+p];
        const float mz = scur[CN*3+p*3+2] + coef * kprev[5*CN+p];
        jt[tid - JC][1] = make_float4(mx, my, mz, 0.f);
    }

    // i-point data (same on-the-fly stmp), PTS=4 points per thread.
    float nx[PTS], ny[PTS], nz[PTS], c2[PTS];   // n = -2*ci', c2 = |ci'|^2
    float mx[PTS], my[PTS], mz[PTS];
    float gx[PTS], gy[PTS], gz[PTS], hx[PTS], hy[PTS], hz[PTS], W[PTS];
#pragma unroll
    for (int q = 0; q < PTS; ++q) {
        const int i = blockIdx.x * IGRP + tid + q * TPB;
        const float cx = (scur[i*3+0] + coef * kprev[0*CN+i]) * CSCALE;
        const float cy = (scur[i*3+1] + coef * kprev[1*CN+i]) * CSCALE;
        const float cz = (scur[i*3+2] + coef * kprev[2*CN+i]) * CSCALE;
        nx[q] = -2.f*cx; ny[q] = -2.f*cy; nz[q] = -2.f*cz;
        c2[q] = fmaf(cx,cx, fmaf(cy,cy, cz*cz));
        mx[q] = scur[CN*3+i*3+0] + coef * kprev[3*CN+i];
        my[q] = scur[CN*3+i*3+1] + coef * kprev[4*CN+i];
        mz[q] = scur[CN*3+i*3+2] + coef * kprev[5*CN+i];
        gx[q]=0.f; gy[q]=0.f; gz[q]=0.f; hx[q]=0.f; hy[q]=0.f; hz[q]=0.f; W[q]=0.f;
    }

    __syncthreads();

#pragma unroll 2
    for (int j = 0; j < JC; ++j) {
        const float4 A = jt[j][0];   // ds_read_b128 broadcast
        const float4 M = jt[j][1];
#pragma unroll
        for (int q = 0; q < PTS; ++q) {
            const float d2 = fmaf(nx[q], A.x, fmaf(ny[q], A.y, fmaf(nz[q], A.z, c2[q] + A.w)));
            const float e  = __builtin_amdgcn_exp2f(-d2);
            const float md = fmaf(mx[q], M.x, fmaf(my[q], M.y, mz[q] * M.z));
            const float w  = md * e;
            gx[q] = fmaf(e, M.x, gx[q]); gy[q] = fmaf(e, M.y, gy[q]); gz[q] = fmaf(e, M.z, gz[q]);
            W[q] += w;
            hx[q] = fmaf(w, A.x, hx[q]); hy[q] = fmaf(w, A.y, hy[q]); hz[q] = fmaf(w, A.z, hz[q]);
        }
    }

    // force = ci'*W - h (scaled units); dm = FSCALE * force. SJ adds/address, fp32 noise ~1e-6.
#pragma unroll
    for (int q = 0; q < PTS; ++q) {
        const int i = blockIdx.x * IGRP + tid + q * TPB;
        const float cx = -0.5f * nx[q], cy = -0.5f * ny[q], cz = -0.5f * nz[q];
        atomicAdd(&kout[0*CN+i], gx[q]);
        atomicAdd(&kout[1*CN+i], gy[q]);
        atomicAdd(&kout[2*CN+i], gz[q]);
        atomicAdd(&kout[3*CN+i], FSCALE * fmaf(cx, W[q], -hx[q]));
        atomicAdd(&kout[4*CN+i], FSCALE * fmaf(cy, W[q], -hy[q]));
        atomicAdd(&kout[5*CN+i], FSCALE * fmaf(cz, W[q], -hz[q]));
    }
}

// RK4 combine + output echo + k-rezero. idx over [0, 6*CN): plane = idx>>13, i = idx&8191.
__global__ __launch_bounds__(256) void advance_kernel(
    float* __restrict__ scur,
    float* __restrict__ k1, float* __restrict__ k2,
    float* __restrict__ k3, float* __restrict__ k4,
    float* __restrict__ outslot, float dt6)
{
    const int idx = blockIdx.x * 256 + threadIdx.x;
    if (idx >= 6 * CN) return;
    const int plane = idx >> 13, i = idx & (CN - 1);
    const int comp = (plane >= 3) ? 1 : 0, d = plane - comp * 3;
    const int off = comp * CN * 3 + i * 3 + d;
    const float v = scur[off] + dt6 * (k1[idx] + 2.f * (k2[idx] + k3[idx]) + k4[idx]);
    scur[off]    = v;
    outslot[off] = v;
    k1[idx] = 0.f; k2[idx] = 0.f; k3[idx] = 0.f; k4[idx] = 0.f;
}

__global__ __launch_bounds__(256) void init_kernel(
    const float* __restrict__ mom, const float* __restrict__ cp,
    float* __restrict__ out, float* __restrict__ scur,
    float* __restrict__ kb0, float* __restrict__ kb1,
    float* __restrict__ kb2, float* __restrict__ kb3)
{
    const int idx = blockIdx.x * 256 + threadIdx.x;
    if (idx < 5) out[idx] = 0.25f * (float)idx;      // t_span
    if (idx < 6 * CN) { kb0[idx]=0.f; kb1[idx]=0.f; kb2[idx]=0.f; kb3[idx]=0.f; }
    if (idx < CN * 3) {
        const float cv = cp[idx], mv = mom[idx];
        scur[idx]          = cv;
        scur[CN * 3 + idx] = mv;
        out[5 + idx]            = cv;                // st[0][0] = c0
        out[5 + CN * 3 + idx]   = mv;                // st[0][1] = m0
    }
}

extern "C" void kernel_launch(void* const* d_in, const int* in_sizes, int n_in,
                              void* d_out, int out_size, void* d_ws, size_t ws_size,
                              hipStream_t stream)
{
    const float* mom = (const float*)d_in[0];
    const float* cp  = (const float*)d_in[1];
    float* out = (float*)d_out;
    float* ws  = (float*)d_ws;

    float* scur = ws;                       // SSZ
    float* kb0  = ws + SSZ;                 // 6*CN each
    float* kb1  = kb0 + 6 * CN;
    float* kb2  = kb1 + 6 * CN;
    float* kb3  = kb2 + 6 * CN;

    const float dt  = 0.25f;
    const float dt6 = dt / 6.f;

    init_kernel<<<(6 * CN + 255) / 256, 256, 0, stream>>>(mom, cp, out, scur,
                                                          kb0, kb1, kb2, kb3);
    dim3 dgrid(NIB, SJ);
    const int agrid = (6 * CN + 255) / 256;
    for (int step = 0; step < 4; ++step) {
        float* outslot = out + 5 + (size_t)(step + 1) * SSZ;
        // stage 1 reads kb3 as a zeroed dummy (coef=0) to avoid read/write overlap on kb0
        dyn_kernel<<<dgrid, TPB, 0, stream>>>(scur, kb3, 0.0f,      kb0);
        dyn_kernel<<<dgrid, TPB, 0, stream>>>(scur, kb0, 0.5f * dt, kb1);
        dyn_kernel<<<dgrid, TPB, 0, stream>>>(scur, kb1, 0.5f * dt, kb2);
        dyn_kernel<<<dgrid, TPB, 0, stream>>>(scur, kb2, dt,        kb3);
        advance_kernel<<<agrid, 256, 0, stream>>>(scur, kb0, kb1, kb2, kb3, outslot, dt6);
    }
}